// Round 7
// baseline (21.186 us; speedup 1.0000x reference)
//
#include <hip/hip_runtime.h>

#define LN_EPS 1e-5f

// One block per sample n. 512 threads = one per d column.
// R5 structure + constant-last-row + b128 gathers (rows padded to 48 B).
__global__ __launch_bounds__(512) void choquet_fused_kernel(
    const float* __restrict__ x,      // (N, 8, 512)
    const float* __restrict__ FM,     // (255, 8)
    const float* __restrict__ lnw,    // (8, 512)
    const float* __restrict__ lnb,    // (8, 512)
    const float* __restrict__ prelu,  // (1,)
    float* __restrict__ out)          // (N, 8, 512)
{
    constexpr int D = 512, H = 8;
    // FM rows padded 8 -> 12 dwords (48 B): every row 16B-aligned for b128
    // gathers; start bank (12r mod 32) cycles all 8 quad positions.
    __shared__ float4 fm_s[255 * 3];
    __shared__ float red[16];         // 8 waves x {sum, sumsq}

    const int n = blockIdx.x;
    const int d = threadIdx.x;

    // ---- issue streaming x loads first ----
    const float* xp = x + (size_t)n * 8 * D + d;
    float v0 = __builtin_nontemporal_load(xp + 0 * D);
    float v1 = __builtin_nontemporal_load(xp + 1 * D);
    float v2 = __builtin_nontemporal_load(xp + 2 * D);
    float v3 = __builtin_nontemporal_load(xp + 3 * D);
    float v4 = __builtin_nontemporal_load(xp + 4 * D);
    float v5 = __builtin_nontemporal_load(xp + 5 * D);
    float v6 = __builtin_nontemporal_load(xp + 6 * D);
    float v7 = __builtin_nontemporal_load(xp + 7 * D);

    // stage FM: 510 float4 global loads -> rows of 3 float4 (stride 12 floats)
    if (threadIdx.x < 510) {
        const float4 v = ((const float4*)FM)[threadIdx.x];
        const int r = threadIdx.x >> 1, half = threadIdx.x & 1;
        fm_s[3 * r + half] = v;           // half 0 -> h0..3, half 1 -> h4..7
    }

    // last step's row is always FM[254] (mask == 255): keep in registers
    const float4 last0 = ((const float4*)FM)[254 * 2];
    const float4 last1 = ((const float4*)FM)[254 * 2 + 1];

    int i0 = 0, i1 = 1, i2 = 2, i3 = 3, i4 = 4, i5 = 5, i6 = 6, i7 = 7;

    // Descending sort, value-only compare (ties have zero weight).
#define CE(a, b)                                                              \
    {                                                                         \
        if (v##a < v##b) {                                                    \
            float tv = v##a; v##a = v##b; v##b = tv;                          \
            int   ti = i##a; i##a = i##b; i##b = ti;                          \
        }                                                                     \
    }
    CE(0, 1) CE(2, 3) CE(4, 5) CE(6, 7)
    CE(0, 2) CE(1, 3) CE(4, 6) CE(5, 7)
    CE(1, 2) CE(5, 6) CE(0, 4) CE(3, 7)
    CE(1, 5) CE(2, 6)
    CE(1, 4) CE(3, 6)
    CE(2, 4) CE(3, 5)
    CE(3, 4)
#undef CE

    __syncthreads();   // FM staged

    // Choquet accumulation: latt = (running OR of 2^idx) - 1.
    float y[H];
#pragma unroll
    for (int h = 0; h < H; ++h) y[h] = 0.f;

    int mask = 0;
#define STEP(vs, is, vnext)                                                   \
    {                                                                         \
        mask |= (1 << (is));                                                  \
        const float diff = (vs) - (vnext);                                    \
        const float4* row = &fm_s[3 * (mask - 1)];                            \
        const float4 r0 = row[0], r1 = row[1];                                \
        y[0] += diff * r0.x; y[1] += diff * r0.y;                             \
        y[2] += diff * r0.z; y[3] += diff * r0.w;                             \
        y[4] += diff * r1.x; y[5] += diff * r1.y;                             \
        y[6] += diff * r1.z; y[7] += diff * r1.w;                             \
    }
    STEP(v0, i0, v1)
    STEP(v1, i1, v2)
    STEP(v2, i2, v3)
    STEP(v3, i3, v4)
    STEP(v4, i4, v5)
    STEP(v5, i5, v6)
    STEP(v6, i6, v7)
#undef STEP
    // step 8: mask == 255 always -> constant row, diff = v7
    y[0] += v7 * last0.x; y[1] += v7 * last0.y;
    y[2] += v7 * last0.z; y[3] += v7 * last0.w;
    y[4] += v7 * last1.x; y[5] += v7 * last1.y;
    y[6] += v7 * last1.z; y[7] += v7 * last1.w;

    // ---- issue LN param loads now; latency hides under the reduction ----
    float w[H], b[H];
#pragma unroll
    for (int h = 0; h < H; ++h) { w[h] = lnw[h * D + d]; b[h] = lnb[h * D + d]; }
    const float pw = prelu[0];

    // Block mean/var over H*D = 4096 values.
    float s1 = 0.f, s2 = 0.f;
#pragma unroll
    for (int h = 0; h < H; ++h) { s1 += y[h]; s2 += y[h] * y[h]; }
#pragma unroll
    for (int off = 32; off > 0; off >>= 1) {
        s1 += __shfl_xor(s1, off);
        s2 += __shfl_xor(s2, off);
    }
    const int wid = threadIdx.x >> 6;
    if ((threadIdx.x & 63) == 0) { red[wid * 2] = s1; red[wid * 2 + 1] = s2; }
    __syncthreads();

    float t1 = 0.f, t2 = 0.f;
#pragma unroll
    for (int wv = 0; wv < 8; ++wv) { t1 += red[wv * 2]; t2 += red[wv * 2 + 1]; }
    const float mean = t1 * (1.0f / 4096.0f);
    float var = t2 * (1.0f / 4096.0f) - mean * mean;
    var = var < 0.f ? 0.f : var;
    const float rstd = rsqrtf(var + LN_EPS);

    float* op = out + (size_t)n * H * D + d;
#pragma unroll
    for (int h = 0; h < H; ++h) {
        float val = (y[h] - mean) * rstd * w[h] + b[h];
        val = val > 0.f ? val : pw * val;
        __builtin_nontemporal_store(val, op + h * D);
    }
}

extern "C" void kernel_launch(void* const* d_in, const int* in_sizes, int n_in,
                              void* d_out, int out_size, void* d_ws, size_t ws_size,
                              hipStream_t stream) {
    const float* x     = (const float*)d_in[0];
    const float* FM    = (const float*)d_in[1];
    const float* lnw   = (const float*)d_in[2];
    const float* lnb   = (const float*)d_in[3];
    const float* prelu = (const float*)d_in[4];
    float* out = (float*)d_out;

    const int N = in_sizes[0] / (8 * 512);
    choquet_fused_kernel<<<N, 512, 0, stream>>>(x, FM, lnw, lnb, prelu, out);
}

// Round 8
// 21.065 us; speedup vs baseline: 1.0057x; 1.0057x over previous
//
#include <hip/hip_runtime.h>

#define LN_EPS 1e-5f

// One block per sample n. 512 threads = one per d column.
// R5 structure + constant-last-row + b128 gathers (rows padded to 48 B).
__global__ __launch_bounds__(512) void choquet_fused_kernel(
    const float* __restrict__ x,      // (N, 8, 512)
    const float* __restrict__ FM,     // (255, 8)
    const float* __restrict__ lnw,    // (8, 512)
    const float* __restrict__ lnb,    // (8, 512)
    const float* __restrict__ prelu,  // (1,)
    float* __restrict__ out)          // (N, 8, 512)
{
    constexpr int D = 512, H = 8;
    // FM rows padded 8 -> 12 dwords (48 B): every row 16B-aligned for b128
    // gathers; start bank (12r mod 32) cycles all 8 quad positions.
    __shared__ float4 fm_s[255 * 3];
    __shared__ float red[16];         // 8 waves x {sum, sumsq}

    const int n = blockIdx.x;
    const int d = threadIdx.x;

    // ---- issue streaming x loads first ----
    const float* xp = x + (size_t)n * 8 * D + d;
    float v0 = __builtin_nontemporal_load(xp + 0 * D);
    float v1 = __builtin_nontemporal_load(xp + 1 * D);
    float v2 = __builtin_nontemporal_load(xp + 2 * D);
    float v3 = __builtin_nontemporal_load(xp + 3 * D);
    float v4 = __builtin_nontemporal_load(xp + 4 * D);
    float v5 = __builtin_nontemporal_load(xp + 5 * D);
    float v6 = __builtin_nontemporal_load(xp + 6 * D);
    float v7 = __builtin_nontemporal_load(xp + 7 * D);

    // stage FM: 510 float4 global loads -> rows of 3 float4 (stride 12 floats)
    if (threadIdx.x < 510) {
        const float4 v = ((const float4*)FM)[threadIdx.x];
        const int r = threadIdx.x >> 1, half = threadIdx.x & 1;
        fm_s[3 * r + half] = v;           // half 0 -> h0..3, half 1 -> h4..7
    }

    // last step's row is always FM[254] (mask == 255): keep in registers
    const float4 last0 = ((const float4*)FM)[254 * 2];
    const float4 last1 = ((const float4*)FM)[254 * 2 + 1];

    int i0 = 0, i1 = 1, i2 = 2, i3 = 3, i4 = 4, i5 = 5, i6 = 6, i7 = 7;

    // Descending sort, value-only compare (ties have zero weight).
#define CE(a, b)                                                              \
    {                                                                         \
        if (v##a < v##b) {                                                    \
            float tv = v##a; v##a = v##b; v##b = tv;                          \
            int   ti = i##a; i##a = i##b; i##b = ti;                          \
        }                                                                     \
    }
    CE(0, 1) CE(2, 3) CE(4, 5) CE(6, 7)
    CE(0, 2) CE(1, 3) CE(4, 6) CE(5, 7)
    CE(1, 2) CE(5, 6) CE(0, 4) CE(3, 7)
    CE(1, 5) CE(2, 6)
    CE(1, 4) CE(3, 6)
    CE(2, 4) CE(3, 5)
    CE(3, 4)
#undef CE

    __syncthreads();   // FM staged

    // Choquet accumulation: latt = (running OR of 2^idx) - 1.
    float y[H];
#pragma unroll
    for (int h = 0; h < H; ++h) y[h] = 0.f;

    int mask = 0;
#define STEP(vs, is, vnext)                                                   \
    {                                                                         \
        mask |= (1 << (is));                                                  \
        const float diff = (vs) - (vnext);                                    \
        const float4* row = &fm_s[3 * (mask - 1)];                            \
        const float4 r0 = row[0], r1 = row[1];                                \
        y[0] += diff * r0.x; y[1] += diff * r0.y;                             \
        y[2] += diff * r0.z; y[3] += diff * r0.w;                             \
        y[4] += diff * r1.x; y[5] += diff * r1.y;                             \
        y[6] += diff * r1.z; y[7] += diff * r1.w;                             \
    }
    STEP(v0, i0, v1)
    STEP(v1, i1, v2)
    STEP(v2, i2, v3)
    STEP(v3, i3, v4)
    STEP(v4, i4, v5)
    STEP(v5, i5, v6)
    STEP(v6, i6, v7)
#undef STEP
    // step 8: mask == 255 always -> constant row, diff = v7
    y[0] += v7 * last0.x; y[1] += v7 * last0.y;
    y[2] += v7 * last0.z; y[3] += v7 * last0.w;
    y[4] += v7 * last1.x; y[5] += v7 * last1.y;
    y[6] += v7 * last1.z; y[7] += v7 * last1.w;

    // ---- issue LN param loads now; latency hides under the reduction ----
    float w[H], b[H];
#pragma unroll
    for (int h = 0; h < H; ++h) { w[h] = lnw[h * D + d]; b[h] = lnb[h * D + d]; }
    const float pw = prelu[0];

    // Block mean/var over H*D = 4096 values.
    float s1 = 0.f, s2 = 0.f;
#pragma unroll
    for (int h = 0; h < H; ++h) { s1 += y[h]; s2 += y[h] * y[h]; }
#pragma unroll
    for (int off = 32; off > 0; off >>= 1) {
        s1 += __shfl_xor(s1, off);
        s2 += __shfl_xor(s2, off);
    }
    const int wid = threadIdx.x >> 6;
    if ((threadIdx.x & 63) == 0) { red[wid * 2] = s1; red[wid * 2 + 1] = s2; }
    __syncthreads();

    float t1 = 0.f, t2 = 0.f;
#pragma unroll
    for (int wv = 0; wv < 8; ++wv) { t1 += red[wv * 2]; t2 += red[wv * 2 + 1]; }
    const float mean = t1 * (1.0f / 4096.0f);
    float var = t2 * (1.0f / 4096.0f) - mean * mean;
    var = var < 0.f ? 0.f : var;
    const float rstd = rsqrtf(var + LN_EPS);

    float* op = out + (size_t)n * H * D + d;
#pragma unroll
    for (int h = 0; h < H; ++h) {
        float val = (y[h] - mean) * rstd * w[h] + b[h];
        val = val > 0.f ? val : pw * val;
        __builtin_nontemporal_store(val, op + h * D);
    }
}

extern "C" void kernel_launch(void* const* d_in, const int* in_sizes, int n_in,
                              void* d_out, int out_size, void* d_ws, size_t ws_size,
                              hipStream_t stream) {
    const float* x     = (const float*)d_in[0];
    const float* FM    = (const float*)d_in[1];
    const float* lnw   = (const float*)d_in[2];
    const float* lnb   = (const float*)d_in[3];
    const float* prelu = (const float*)d_in[4];
    float* out = (float*)d_out;

    const int N = in_sizes[0] / (8 * 512);
    choquet_fused_kernel<<<N, 512, 0, stream>>>(x, FM, lnw, lnb, prelu, out);
}

// Round 9
// 20.993 us; speedup vs baseline: 1.0092x; 1.0034x over previous
//
#include <hip/hip_runtime.h>

#define LN_EPS 1e-5f

// One block per sample n. 512 threads = one per d column.
// R5 structure + constant-last-row + b128 gathers (rows padded to 48 B).
__global__ __launch_bounds__(512) void choquet_fused_kernel(
    const float* __restrict__ x,      // (N, 8, 512)
    const float* __restrict__ FM,     // (255, 8)
    const float* __restrict__ lnw,    // (8, 512)
    const float* __restrict__ lnb,    // (8, 512)
    const float* __restrict__ prelu,  // (1,)
    float* __restrict__ out)          // (N, 8, 512)
{
    constexpr int D = 512, H = 8;
    // FM rows padded 8 -> 12 dwords (48 B): every row 16B-aligned for b128
    // gathers; start bank (12r mod 32) cycles all 8 quad positions.
    __shared__ float4 fm_s[255 * 3];
    __shared__ float red[16];         // 8 waves x {sum, sumsq}

    const int n = blockIdx.x;
    const int d = threadIdx.x;

    // ---- issue streaming x loads first ----
    const float* xp = x + (size_t)n * 8 * D + d;
    float v0 = __builtin_nontemporal_load(xp + 0 * D);
    float v1 = __builtin_nontemporal_load(xp + 1 * D);
    float v2 = __builtin_nontemporal_load(xp + 2 * D);
    float v3 = __builtin_nontemporal_load(xp + 3 * D);
    float v4 = __builtin_nontemporal_load(xp + 4 * D);
    float v5 = __builtin_nontemporal_load(xp + 5 * D);
    float v6 = __builtin_nontemporal_load(xp + 6 * D);
    float v7 = __builtin_nontemporal_load(xp + 7 * D);

    // stage FM: 510 float4 global loads -> rows of 3 float4 (stride 12 floats)
    if (threadIdx.x < 510) {
        const float4 v = ((const float4*)FM)[threadIdx.x];
        const int r = threadIdx.x >> 1, half = threadIdx.x & 1;
        fm_s[3 * r + half] = v;           // half 0 -> h0..3, half 1 -> h4..7
    }

    // last step's row is always FM[254] (mask == 255): keep in registers
    const float4 last0 = ((const float4*)FM)[254 * 2];
    const float4 last1 = ((const float4*)FM)[254 * 2 + 1];

    int i0 = 0, i1 = 1, i2 = 2, i3 = 3, i4 = 4, i5 = 5, i6 = 6, i7 = 7;

    // Descending sort, value-only compare (ties have zero weight).
#define CE(a, b)                                                              \
    {                                                                         \
        if (v##a < v##b) {                                                    \
            float tv = v##a; v##a = v##b; v##b = tv;                          \
            int   ti = i##a; i##a = i##b; i##b = ti;                          \
        }                                                                     \
    }
    CE(0, 1) CE(2, 3) CE(4, 5) CE(6, 7)
    CE(0, 2) CE(1, 3) CE(4, 6) CE(5, 7)
    CE(1, 2) CE(5, 6) CE(0, 4) CE(3, 7)
    CE(1, 5) CE(2, 6)
    CE(1, 4) CE(3, 6)
    CE(2, 4) CE(3, 5)
    CE(3, 4)
#undef CE

    __syncthreads();   // FM staged

    // Choquet accumulation: latt = (running OR of 2^idx) - 1.
    float y[H];
#pragma unroll
    for (int h = 0; h < H; ++h) y[h] = 0.f;

    int mask = 0;
#define STEP(vs, is, vnext)                                                   \
    {                                                                         \
        mask |= (1 << (is));                                                  \
        const float diff = (vs) - (vnext);                                    \
        const float4* row = &fm_s[3 * (mask - 1)];                            \
        const float4 r0 = row[0], r1 = row[1];                                \
        y[0] += diff * r0.x; y[1] += diff * r0.y;                             \
        y[2] += diff * r0.z; y[3] += diff * r0.w;                             \
        y[4] += diff * r1.x; y[5] += diff * r1.y;                             \
        y[6] += diff * r1.z; y[7] += diff * r1.w;                             \
    }
    STEP(v0, i0, v1)
    STEP(v1, i1, v2)
    STEP(v2, i2, v3)
    STEP(v3, i3, v4)
    STEP(v4, i4, v5)
    STEP(v5, i5, v6)
    STEP(v6, i6, v7)
#undef STEP
    // step 8: mask == 255 always -> constant row, diff = v7
    y[0] += v7 * last0.x; y[1] += v7 * last0.y;
    y[2] += v7 * last0.z; y[3] += v7 * last0.w;
    y[4] += v7 * last1.x; y[5] += v7 * last1.y;
    y[6] += v7 * last1.z; y[7] += v7 * last1.w;

    // ---- issue LN param loads now; latency hides under the reduction ----
    float w[H], b[H];
#pragma unroll
    for (int h = 0; h < H; ++h) { w[h] = lnw[h * D + d]; b[h] = lnb[h * D + d]; }
    const float pw = prelu[0];

    // Block mean/var over H*D = 4096 values.
    float s1 = 0.f, s2 = 0.f;
#pragma unroll
    for (int h = 0; h < H; ++h) { s1 += y[h]; s2 += y[h] * y[h]; }
#pragma unroll
    for (int off = 32; off > 0; off >>= 1) {
        s1 += __shfl_xor(s1, off);
        s2 += __shfl_xor(s2, off);
    }
    const int wid = threadIdx.x >> 6;
    if ((threadIdx.x & 63) == 0) { red[wid * 2] = s1; red[wid * 2 + 1] = s2; }
    __syncthreads();

    float t1 = 0.f, t2 = 0.f;
#pragma unroll
    for (int wv = 0; wv < 8; ++wv) { t1 += red[wv * 2]; t2 += red[wv * 2 + 1]; }
    const float mean = t1 * (1.0f / 4096.0f);
    float var = t2 * (1.0f / 4096.0f) - mean * mean;
    var = var < 0.f ? 0.f : var;
    const float rstd = rsqrtf(var + LN_EPS);

    float* op = out + (size_t)n * H * D + d;
#pragma unroll
    for (int h = 0; h < H; ++h) {
        float val = (y[h] - mean) * rstd * w[h] + b[h];
        val = val > 0.f ? val : pw * val;
        __builtin_nontemporal_store(val, op + h * D);
    }
}

extern "C" void kernel_launch(void* const* d_in, const int* in_sizes, int n_in,
                              void* d_out, int out_size, void* d_ws, size_t ws_size,
                              hipStream_t stream) {
    const float* x     = (const float*)d_in[0];
    const float* FM    = (const float*)d_in[1];
    const float* lnw   = (const float*)d_in[2];
    const float* lnb   = (const float*)d_in[3];
    const float* prelu = (const float*)d_in[4];
    float* out = (float*)d_out;

    const int N = in_sizes[0] / (8 * 512);
    choquet_fused_kernel<<<N, 512, 0, stream>>>(x, FM, lnw, lnb, prelu, out);
}